// Round 2
// baseline (680.425 us; speedup 1.0000x reference)
//
#include <hip/hip_runtime.h>
#include <hip/hip_bf16.h>

typedef __attribute__((ext_vector_type(8))) short bf16x8;
typedef __attribute__((ext_vector_type(4))) short bf16x4;
typedef __attribute__((ext_vector_type(4))) float f32x4;

#define S_LEN 2048
#define DMODEL 2048
#define NQH 16
#define NKVH 4
#define DK 128

__device__ __forceinline__ float b2f(short u) {
  union { unsigned int i; float f; } x;
  x.i = ((unsigned int)(unsigned short)u) << 16;
  return x.f;
}
// round-to-nearest-even f32 -> bf16 (finite inputs only)
__device__ __forceinline__ short f2b(float f) {
  union { float f; unsigned int i; } x; x.f = f;
  unsigned int r = (x.i + 0x7fffu + ((x.i >> 16) & 1u)) >> 16;
  return (short)r;
}
__device__ __forceinline__ f32x4 mfma16(bf16x8 a, bf16x8 b, f32x4 c) {
  return __builtin_amdgcn_mfma_f32_16x16x32_bf16(a, b, c, 0, 0, 0);
}
__device__ __forceinline__ void async16(short* lds, const short* g) {
  __builtin_amdgcn_global_load_lds(
      (const __attribute__((address_space(1))) unsigned int*)(const void*)g,
      (__attribute__((address_space(3))) unsigned int*)(void*)lds, 16, 0, 0);
}

// ---------------------------------------------------------------- f32 -> bf16 convert
__global__ void f32_to_bf16(const float* __restrict__ in, short* __restrict__ out, int n4) {
  int i = blockIdx.x * blockDim.x + threadIdx.x;
  if (i >= n4) return;
  float4 v = ((const float4*)in)[i];
  bf16x4 o;
  o[0] = f2b(v.x); o[1] = f2b(v.y); o[2] = f2b(v.z); o[3] = f2b(v.w);
  ((bf16x4*)out)[i] = o;
}

// ---------------------------------------------------------------- transpose f32 -> bf16
__global__ void transpose_f2b(const float* __restrict__ in, short* __restrict__ out,
                              int R, int C) {
  __shared__ short t[32][33];
  int c0 = blockIdx.x * 32, r0 = blockIdx.y * 32;
  int tx = threadIdx.x, ty = threadIdx.y;  // block (32,8)
#pragma unroll
  for (int i = 0; i < 32; i += 8)
    t[ty + i][tx] = f2b(in[(size_t)(r0 + ty + i) * C + c0 + tx]);
  __syncthreads();
#pragma unroll
  for (int i = 0; i < 32; i += 8)
    out[(size_t)(c0 + ty + i) * R + r0 + tx] = t[tx][ty + i];
}

// ---------------------------------------------------------------- GEMM (A row-major MxK bf16, BT row-major NxK bf16)
// MODE 0: plain C write (f32, MxN)
// MODE 1: Q epilogue: RoPE + RMSNorm + gamma + 1/sqrt(DK), out -> Qr[(b*16+h)][s][d] bf16
// MODE 2: K epilogue: RoPE + RMSNorm + gamma,              out -> Kr[(b*4+h)][s][d] bf16
// MODE 3: V epilogue: transpose,                           out -> Vt[(b*4+h)][d][s] bf16
template <int MODE>
__global__ __launch_bounds__(256) void gemm_bt(const short* __restrict__ A,
                                               const short* __restrict__ BT,
                                               short* __restrict__ out,
                                               float* __restrict__ outf,
                                               const float* __restrict__ gamma,
                                               int M, int N, int K) {
  constexpr int CS_LD = 136;  // padded -> avoids LDS bank conflicts on row/col access
  constexpr int SM_SHORTS = (MODE == 0) ? (128 * 32 * 2) : (128 * CS_LD);
  __shared__ __align__(16) short smem[SM_SHORTS];
  short* As = smem;
  short* Bs = smem + 128 * 32;

  const int tid = threadIdx.x;
  const int lane = tid & 63;
  const int w = tid >> 6;
  const int wm = w >> 1, wn = w & 1;
  const int l15 = lane & 15, lg = lane >> 4;
  const int mb = blockIdx.x, nb = blockIdx.y;

  f32x4 acc[4][4] = {};

  const short* Ab = A + (size_t)mb * 128 * K;
  const short* Bb = BT + (size_t)nb * 128 * K;

  for (int k0 = 0; k0 < K; k0 += 32) {
    __syncthreads();
    // stage 128x32 A and B tiles: wave w stages rows [w*32, w*32+32)
    {
      const int rb0 = w * 32;
      const int rb1 = w * 32 + 16;
      const int mr = lane >> 2;
      const int kg = (lane & 3) * 8;
      async16(As + rb0 * 32, Ab + (size_t)(rb0 + mr) * K + k0 + kg);
      async16(As + rb1 * 32, Ab + (size_t)(rb1 + mr) * K + k0 + kg);
      async16(Bs + rb0 * 32, Bb + (size_t)(rb0 + mr) * K + k0 + kg);
      async16(Bs + rb1 * 32, Bb + (size_t)(rb1 + mr) * K + k0 + kg);
    }
    __syncthreads();
    bf16x8 af[4], bfr[4];
#pragma unroll
    for (int mt = 0; mt < 4; ++mt)
      af[mt] = *(const bf16x8*)(As + (wm * 64 + mt * 16 + l15) * 32 + lg * 8);
#pragma unroll
    for (int nt = 0; nt < 4; ++nt)
      bfr[nt] = *(const bf16x8*)(Bs + (wn * 64 + nt * 16 + l15) * 32 + lg * 8);
#pragma unroll
    for (int mt = 0; mt < 4; ++mt)
#pragma unroll
      for (int nt = 0; nt < 4; ++nt)
        acc[mt][nt] = mfma16(af[mt], bfr[nt], acc[mt][nt]);
  }

  if (MODE == 0) {
#pragma unroll
    for (int mt = 0; mt < 4; ++mt) {
      const int row = mb * 128 + wm * 64 + mt * 16 + lg * 4;
#pragma unroll
      for (int nt = 0; nt < 4; ++nt) {
        const int col = nb * 128 + wn * 64 + nt * 16 + l15;
#pragma unroll
        for (int r = 0; r < 4; ++r)
          outf[(size_t)(row + r) * N + col] = acc[mt][nt][r];
      }
    }
    return;
  }

  // ---- epilogue: stage C tile (bf16) to LDS, then fused transform ----
  __syncthreads();
  short* Cs = smem;
#pragma unroll
  for (int mt = 0; mt < 4; ++mt)
#pragma unroll
    for (int nt = 0; nt < 4; ++nt)
#pragma unroll
      for (int r = 0; r < 4; ++r)
        Cs[(wm * 64 + mt * 16 + lg * 4 + r) * CS_LD + wn * 64 + nt * 16 + l15] =
            f2b(acc[mt][nt][r]);
  __syncthreads();

  const int srow0 = mb * 128;
  const int b = srow0 >> 11;  // 2048 rows per batch
  const int h = nb;

  if (MODE == 1 || MODE == 2) {
    const int r = tid >> 1, part = tid & 1;  // 2 lanes per row
    const int s = (srow0 + r) & 2047;
    const float pos = (float)s;
    float ss = 0.f;
    // RoPE in place: part0 writes d in [0,64), part1 writes [64,128)
    for (int d = 0; d < 64; ++d) {
      float t1 = b2f(Cs[r * CS_LD + d]);
      float t2 = b2f(Cs[r * CS_LD + d + 64]);
      float ang = pos * __expf((float)d * -0.14391157f);  // ln(10000)/64
      float c, sn;
      __sincosf(ang, &sn, &c);
      float o = part ? (t2 * c + t1 * sn) : (t1 * c - t2 * sn);
      ss += o * o;
      Cs[r * CS_LD + part * 64 + d] = f2b(o);
    }
    ss += __shfl_xor(ss, 1);
    float inv = rsqrtf(ss * (1.0f / 128.0f) + 1e-6f);
    if (MODE == 1) inv *= 0.08838834764831845f;  // 1/sqrt(DK) softmax scale
    const int NH = (MODE == 1) ? NQH : NKVH;
    short* ob = out + ((size_t)(b * NH + h) * S_LEN + s) * DK;
#pragma unroll
    for (int d0 = 0; d0 < 64; d0 += 8) {
      const int d = part * 64 + d0;
      bf16x8 v;
#pragma unroll
      for (int j = 0; j < 8; ++j)
        v[j] = f2b(b2f(Cs[r * CS_LD + d + j]) * inv * gamma[d + j]);
      *(bf16x8*)(ob + d) = v;
    }
  } else {  // MODE 3: V transpose -> Vt[(b*4+h)][d][s]
    const int d = tid & 127;
    const int sh = tid >> 7;
    const int sbase = (srow0 & 2047) + sh * 64;
    short* ob = out + ((size_t)(b * NKVH + h) * DK + d) * S_LEN + sbase;
    for (int i0 = 0; i0 < 64; i0 += 8) {
      bf16x8 v;
#pragma unroll
      for (int j = 0; j < 8; ++j) v[j] = Cs[(sh * 64 + i0 + j) * CS_LD + d];
      *(bf16x8*)(ob + i0) = v;
    }
  }
}

// ---------------------------------------------------------------- flash attention (causal)
// grid: (32 q-tiles, 32 b*16+qh), block 256 (4 waves x 16 q-rows)
__global__ __launch_bounds__(256) void attn_kernel(const short* __restrict__ Qr,
                                                   const short* __restrict__ Kr,
                                                   const short* __restrict__ Vt,
                                                   short* __restrict__ AO) {
  const int qt = blockIdx.x;
  const int bh = blockIdx.y;
  const int b = bh >> 4, qh = bh & 15;
  const int kvh = qh >> 2;
  const short* Qb = Qr + (size_t)bh * S_LEN * DK;
  const short* Kb = Kr + (size_t)(b * NKVH + kvh) * S_LEN * DK;
  const short* Vb = Vt + (size_t)(b * NKVH + kvh) * DK * S_LEN;
  const int tid = threadIdx.x, lane = tid & 63, w = tid >> 6;
  const int l15 = lane & 15, lg = lane >> 4;
  __shared__ __align__(16) short P[4][16][72];  // per-wave P tile, padded stride
  const int q0 = qt * 64 + w * 16;

  bf16x8 aq[4];
#pragma unroll
  for (int kk = 0; kk < 4; ++kk)
    aq[kk] = *(const bf16x8*)(Qb + (size_t)(q0 + l15) * DK + kk * 32 + lg * 8);

  f32x4 acco[8] = {};
  float m[4], lsum[4];
#pragma unroll
  for (int r = 0; r < 4; ++r) { m[r] = -1e30f; lsum[r] = 0.f; }

  for (int kt = 0; kt <= qt; ++kt) {
    const int kb = kt * 64;
    f32x4 sc[4] = {};
#pragma unroll
    for (int nt = 0; nt < 4; ++nt)
#pragma unroll
      for (int kk = 0; kk < 4; ++kk) {
        bf16x8 bk = *(const bf16x8*)(Kb + (size_t)(kb + nt * 16 + l15) * DK + kk * 32 + lg * 8);
        sc[nt] = mfma16(aq[kk], bk, sc[nt]);
      }
    if (kt == qt) {  // causal mask on diagonal tile
#pragma unroll
      for (int nt = 0; nt < 4; ++nt) {
        const int k = kb + nt * 16 + l15;
#pragma unroll
        for (int r = 0; r < 4; ++r)
          if (k > q0 + lg * 4 + r) sc[nt][r] = -1e30f;
      }
    }
    float pm[4];
#pragma unroll
    for (int r = 0; r < 4; ++r)
      pm[r] = fmaxf(fmaxf(sc[0][r], sc[1][r]), fmaxf(sc[2][r], sc[3][r]));
#pragma unroll
    for (int r = 0; r < 4; ++r) {
      pm[r] = fmaxf(pm[r], __shfl_xor(pm[r], 1));
      pm[r] = fmaxf(pm[r], __shfl_xor(pm[r], 2));
      pm[r] = fmaxf(pm[r], __shfl_xor(pm[r], 4));
      pm[r] = fmaxf(pm[r], __shfl_xor(pm[r], 8));
    }
    float alpha[4];
#pragma unroll
    for (int r = 0; r < 4; ++r) {
      const float nm = fmaxf(m[r], pm[r]);
      alpha[r] = __expf(m[r] - nm);
      m[r] = nm;
    }
    float psum[4] = {0.f, 0.f, 0.f, 0.f};
#pragma unroll
    for (int nt = 0; nt < 4; ++nt)
#pragma unroll
      for (int r = 0; r < 4; ++r) {
        const float p = __expf(sc[nt][r] - m[r]);
        psum[r] += p;
        P[w][lg * 4 + r][nt * 16 + l15] = f2b(p);
      }
#pragma unroll
    for (int r = 0; r < 4; ++r) lsum[r] = lsum[r] * alpha[r] + psum[r];
#pragma unroll
    for (int dt = 0; dt < 8; ++dt)
#pragma unroll
      for (int r = 0; r < 4; ++r) acco[dt][r] *= alpha[r];
#pragma unroll
    for (int kk = 0; kk < 2; ++kk) {
      bf16x8 ap = *(const bf16x8*)(&P[w][l15][kk * 32 + lg * 8]);
#pragma unroll
      for (int dt = 0; dt < 8; ++dt) {
        bf16x8 bv = *(const bf16x8*)(Vb + (size_t)(dt * 16 + l15) * S_LEN + kb + kk * 32 + lg * 8);
        acco[dt] = mfma16(ap, bv, acco[dt]);
      }
    }
  }
#pragma unroll
  for (int r = 0; r < 4; ++r) {
    lsum[r] += __shfl_xor(lsum[r], 1);
    lsum[r] += __shfl_xor(lsum[r], 2);
    lsum[r] += __shfl_xor(lsum[r], 4);
    lsum[r] += __shfl_xor(lsum[r], 8);
  }
  float inv[4];
#pragma unroll
  for (int r = 0; r < 4; ++r) inv[r] = 1.0f / lsum[r];
  short* ob = AO + (size_t)(b * S_LEN + q0) * (NQH * DK) + qh * DK;
#pragma unroll
  for (int dt = 0; dt < 8; ++dt)
#pragma unroll
    for (int r = 0; r < 4; ++r)
      ob[(size_t)(lg * 4 + r) * (NQH * DK) + dt * 16 + l15] = f2b(acco[dt][r] * inv[r]);
}

// ---------------------------------------------------------------- launch
extern "C" void kernel_launch(void* const* d_in, const int* in_sizes, int n_in,
                              void* d_out, int out_size, void* d_ws, size_t ws_size,
                              hipStream_t stream) {
  const float* x = (const float*)d_in[0];
  // d_in[1] = mask (causal tril) — implemented analytically
  const float* Wq = (const float*)d_in[2];
  const float* Wk = (const float*)d_in[3];
  const float* Wv = (const float*)d_in[4];
  const float* Wfc = (const float*)d_in[5];
  const float* qg = (const float*)d_in[6];
  const float* kg = (const float*)d_in[7];

  short* ws = (short*)d_ws;
  short* xb = ws;                                   // 4096*2048 (also reused as AO)
  short* WqT = xb + (size_t)4096 * 2048;            // 2048*2048
  short* WkT = WqT + (size_t)2048 * 2048;           // 512*2048
  short* WvT = WkT + (size_t)512 * 2048;            // 512*2048
  short* WfcT = WvT + (size_t)512 * 2048;           // 2048*2048
  short* Qr = WfcT + (size_t)2048 * 2048;           // 32*2048*128
  short* Kr = Qr + (size_t)32 * 2048 * 128;         // 8*2048*128
  short* Vt = Kr + (size_t)8 * 2048 * 128;          // 8*128*2048
  short* AO = xb;                                   // alias: x dead after V GEMM

  f32_to_bf16<<<(4096 * 2048 / 4 + 255) / 256, 256, 0, stream>>>(x, xb, 4096 * 2048 / 4);

  dim3 tb(32, 8);
  transpose_f2b<<<dim3(2048 / 32, 2048 / 32), tb, 0, stream>>>(Wq, WqT, 2048, 2048);
  transpose_f2b<<<dim3(512 / 32, 2048 / 32), tb, 0, stream>>>(Wk, WkT, 2048, 512);
  transpose_f2b<<<dim3(512 / 32, 2048 / 32), tb, 0, stream>>>(Wv, WvT, 2048, 512);
  transpose_f2b<<<dim3(2048 / 32, 2048 / 32), tb, 0, stream>>>(Wfc, WfcT, 2048, 2048);

  gemm_bt<1><<<dim3(32, 16), 256, 0, stream>>>(xb, WqT, Qr, nullptr, qg, 4096, 2048, 2048);
  gemm_bt<2><<<dim3(32, 4), 256, 0, stream>>>(xb, WkT, Kr, nullptr, kg, 4096, 512, 2048);
  gemm_bt<3><<<dim3(32, 4), 256, 0, stream>>>(xb, WvT, Vt, nullptr, nullptr, 4096, 512, 2048);

  attn_kernel<<<dim3(32, 32), 256, 0, stream>>>(Qr, Kr, Vt, AO);

  gemm_bt<0><<<dim3(32, 16), 256, 0, stream>>>(AO, WfcT, nullptr, (float*)d_out, nullptr,
                                               4096, 2048, 2048);
}

// Round 3
// 323.093 us; speedup vs baseline: 2.1060x; 2.1060x over previous
//
#include <hip/hip_runtime.h>
#include <hip/hip_bf16.h>

typedef __attribute__((ext_vector_type(8))) short bf16x8;
typedef __attribute__((ext_vector_type(4))) short bf16x4;
typedef __attribute__((ext_vector_type(4))) float f32x4;

#define S_LEN 2048
#define DMODEL 2048
#define NQH 16
#define NKVH 4
#define DK 128

__device__ __forceinline__ float b2f(short u) {
  union { unsigned int i; float f; } x;
  x.i = ((unsigned int)(unsigned short)u) << 16;
  return x.f;
}
// round-to-nearest-even f32 -> bf16 (finite inputs only)
__device__ __forceinline__ short f2b(float f) {
  union { float f; unsigned int i; } x; x.f = f;
  unsigned int r = (x.i + 0x7fffu + ((x.i >> 16) & 1u)) >> 16;
  return (short)r;
}
__device__ __forceinline__ f32x4 mfma16(bf16x8 a, bf16x8 b, f32x4 c) {
  return __builtin_amdgcn_mfma_f32_16x16x32_bf16(a, b, c, 0, 0, 0);
}
__device__ __forceinline__ void async16(short* lds, const short* g) {
  __builtin_amdgcn_global_load_lds(
      (const __attribute__((address_space(1))) unsigned int*)(const void*)g,
      (__attribute__((address_space(3))) unsigned int*)(void*)lds, 16, 0, 0);
}

// ---------------------------------------------------------------- f32 -> bf16 convert
__global__ void f32_to_bf16(const float* __restrict__ in, short* __restrict__ out, int n4) {
  int i = blockIdx.x * blockDim.x + threadIdx.x;
  if (i >= n4) return;
  float4 v = ((const float4*)in)[i];
  bf16x4 o;
  o[0] = f2b(v.x); o[1] = f2b(v.y); o[2] = f2b(v.z); o[3] = f2b(v.w);
  ((bf16x4*)out)[i] = o;
}

// ---------------------------------------------------------------- RoPE cos/sin table
// rt[s*128 + d] = cos(s * base^(-d/64)), rt[s*128 + 64 + d] = sin(...)
__global__ void rope_table(float* __restrict__ rt) {
  int i = blockIdx.x * blockDim.x + threadIdx.x;  // 2048*64
  int s = i >> 6, d = i & 63;
  float ang = (float)s * __expf((float)d * -0.14391157f);  // ln(10000)/64
  float c, sn;
  __sincosf(ang, &sn, &c);
  rt[s * 128 + d] = c;
  rt[s * 128 + 64 + d] = sn;
}

// ---------------------------------------------------------------- transpose f32 -> bf16
__global__ void transpose_f2b(const float* __restrict__ in, short* __restrict__ out,
                              int R, int C) {
  __shared__ short t[32][33];
  int c0 = blockIdx.x * 32, r0 = blockIdx.y * 32;
  int tx = threadIdx.x, ty = threadIdx.y;  // block (32,8)
#pragma unroll
  for (int i = 0; i < 32; i += 8)
    t[ty + i][tx] = f2b(in[(size_t)(r0 + ty + i) * C + c0 + tx]);
  __syncthreads();
#pragma unroll
  for (int i = 0; i < 32; i += 8)
    out[(size_t)(c0 + ty + i) * R + r0 + tx] = t[tx][ty + i];
}

// ---------------------------------------------------------------- GEMM (A row-major MxK bf16, BT row-major NxK bf16)
// MODE 0: plain C write (f32, MxN)
// MODE 1: Q epilogue: RoPE + RMSNorm + gamma + 1/sqrt(DK), out -> Qr[(b*16+h)][s][d] bf16
// MODE 2: K epilogue: RoPE + RMSNorm + gamma,              out -> Kr[(b*4+h)][s][d] bf16
// MODE 3: V epilogue: transpose,                           out -> Vt[(b*4+h)][d][s] bf16
template <int MODE>
__global__ __launch_bounds__(256) void gemm_bt(const short* __restrict__ A,
                                               const short* __restrict__ BT,
                                               short* __restrict__ out,
                                               float* __restrict__ outf,
                                               const float* __restrict__ gamma,
                                               const float* __restrict__ ropeT,
                                               int M, int N, int K) {
  constexpr int CS_LD = 136;  // padded -> avoids LDS bank conflicts on row/col access
  constexpr int SM_SHORTS = (MODE == 0) ? (128 * 32 * 2) : (128 * CS_LD);
  __shared__ __align__(16) short smem[SM_SHORTS];
  short* As = smem;
  short* Bs = smem + 128 * 32;

  const int tid = threadIdx.x;
  const int lane = tid & 63;
  const int w = tid >> 6;
  const int wm = w >> 1, wn = w & 1;
  const int l15 = lane & 15, lg = lane >> 4;
  const int mb = blockIdx.x, nb = blockIdx.y;

  f32x4 acc[4][4] = {};

  const short* Ab = A + (size_t)mb * 128 * K;
  const short* Bb = BT + (size_t)nb * 128 * K;

  for (int k0 = 0; k0 < K; k0 += 32) {
    __syncthreads();
    // stage 128x32 A and B tiles: wave w stages rows [w*32, w*32+32)
    {
      const int rb0 = w * 32;
      const int rb1 = w * 32 + 16;
      const int mr = lane >> 2;
      const int kg = (lane & 3) * 8;
      async16(As + rb0 * 32, Ab + (size_t)(rb0 + mr) * K + k0 + kg);
      async16(As + rb1 * 32, Ab + (size_t)(rb1 + mr) * K + k0 + kg);
      async16(Bs + rb0 * 32, Bb + (size_t)(rb0 + mr) * K + k0 + kg);
      async16(Bs + rb1 * 32, Bb + (size_t)(rb1 + mr) * K + k0 + kg);
    }
    __syncthreads();
    bf16x8 af[4], bfr[4];
#pragma unroll
    for (int mt = 0; mt < 4; ++mt)
      af[mt] = *(const bf16x8*)(As + (wm * 64 + mt * 16 + l15) * 32 + lg * 8);
#pragma unroll
    for (int nt = 0; nt < 4; ++nt)
      bfr[nt] = *(const bf16x8*)(Bs + (wn * 64 + nt * 16 + l15) * 32 + lg * 8);
#pragma unroll
    for (int mt = 0; mt < 4; ++mt)
#pragma unroll
      for (int nt = 0; nt < 4; ++nt)
        acc[mt][nt] = mfma16(af[mt], bfr[nt], acc[mt][nt]);
  }

  if (MODE == 0) {
#pragma unroll
    for (int mt = 0; mt < 4; ++mt) {
      const int row = mb * 128 + wm * 64 + mt * 16 + lg * 4;
#pragma unroll
      for (int nt = 0; nt < 4; ++nt) {
        const int col = nb * 128 + wn * 64 + nt * 16 + l15;
#pragma unroll
        for (int r = 0; r < 4; ++r)
          outf[(size_t)(row + r) * N + col] = acc[mt][nt][r];
      }
    }
    return;
  }

  // ---- epilogue: stage C tile (bf16) to LDS, then fused transform ----
  __syncthreads();
  short* Cs = smem;
#pragma unroll
  for (int mt = 0; mt < 4; ++mt)
#pragma unroll
    for (int nt = 0; nt < 4; ++nt)
#pragma unroll
      for (int r = 0; r < 4; ++r)
        Cs[(wm * 64 + mt * 16 + lg * 4 + r) * CS_LD + wn * 64 + nt * 16 + l15] =
            f2b(acc[mt][nt][r]);
  __syncthreads();

  const int srow0 = mb * 128;
  const int b = srow0 >> 11;  // 2048 rows per batch
  const int h = nb;

  if (MODE == 1 || MODE == 2) {
    const int r = tid >> 1, part = tid & 1;  // 2 lanes per row
    const int s = (srow0 + r) & 2047;
    const float* rt = ropeT + (size_t)s * 128;
    float ss = 0.f;
    // RoPE in place: part0 writes d in [0,64), part1 writes [64,128)
    for (int d = 0; d < 64; ++d) {
      float t1 = b2f(Cs[r * CS_LD + d]);
      float t2 = b2f(Cs[r * CS_LD + d + 64]);
      float c = rt[d], sn = rt[64 + d];
      float o = part ? (t2 * c + t1 * sn) : (t1 * c - t2 * sn);
      ss += o * o;
      Cs[r * CS_LD + part * 64 + d] = f2b(o);
    }
    ss += __shfl_xor(ss, 1);
    float inv = rsqrtf(ss * (1.0f / 128.0f) + 1e-6f);
    if (MODE == 1) inv *= 0.08838834764831845f;  // 1/sqrt(DK) softmax scale
    const int NH = (MODE == 1) ? NQH : NKVH;
    short* ob = out + ((size_t)(b * NH + h) * S_LEN + s) * DK;
#pragma unroll
    for (int d0 = 0; d0 < 64; d0 += 8) {
      const int d = part * 64 + d0;
      bf16x8 v;
#pragma unroll
      for (int j = 0; j < 8; ++j)
        v[j] = f2b(b2f(Cs[r * CS_LD + d + j]) * inv * gamma[d + j]);
      *(bf16x8*)(ob + d) = v;
    }
  } else {  // MODE 3: V transpose -> Vt[(b*4+h)][d][s]
    const int d = tid & 127;
    const int sh = tid >> 7;
    const int sbase = (srow0 & 2047) + sh * 64;
    short* ob = out + ((size_t)(b * NKVH + h) * DK + d) * S_LEN + sbase;
    for (int i0 = 0; i0 < 64; i0 += 8) {
      bf16x8 v;
#pragma unroll
      for (int j = 0; j < 8; ++j) v[j] = Cs[(sh * 64 + i0 + j) * CS_LD + d];
      *(bf16x8*)(ob + i0) = v;
    }
  }
}

// ---------------------------------------------------------------- flash attention v2
// Stage one K/V k-tile (64 keys) into LDS, XOR-swizzled, via per-lane pre-swizzled
// global source addresses (LDS dest is linear: base + lane*16).
// K LDS layout: row(key)-major 64x128, byte = row*256 + (col ^ ((row&7)<<4))
// V LDS layout: d-major 128x64,        byte = row*128 + (col ^ ((row&7)<<4))
__device__ __forceinline__ void stage_kv(const short* __restrict__ Kb,
                                         const short* __restrict__ Vb, int kb,
                                         short* Ks, short* Vs, int w, int lane) {
#pragma unroll
  for (int i = 0; i < 4; ++i) {
    const int c = 4 * w + i;
    const int krow = c * 4 + (lane >> 4);
    const int kcol = (((lane & 15) * 16) ^ ((krow & 7) << 4)) >> 1;
    async16(Ks + c * 512, Kb + (size_t)(kb + krow) * DK + kcol);
    const int vrow = c * 8 + (lane >> 3);
    const int vcol = (((lane & 7) * 16) ^ ((vrow & 7) << 4)) >> 1;
    async16(Vs + c * 512, Vb + (size_t)vrow * S_LEN + kb + vcol);
  }
}

__device__ __forceinline__ void sm_pv(f32x4* sc, float* m, float* lsum, f32x4* acco,
                                      const short* Vc, short* Pw, int q0, bool diag,
                                      int kb, int l15, int lg) {
  if (diag) {
#pragma unroll
    for (int nt = 0; nt < 4; ++nt) {
      const int k = kb + nt * 16 + l15;
#pragma unroll
      for (int r = 0; r < 4; ++r)
        if (k > q0 + lg * 4 + r) sc[nt][r] = -1e30f;
    }
  }
  float pm[4];
#pragma unroll
  for (int r = 0; r < 4; ++r)
    pm[r] = fmaxf(fmaxf(sc[0][r], sc[1][r]), fmaxf(sc[2][r], sc[3][r]));
#pragma unroll
  for (int r = 0; r < 4; ++r) {
    pm[r] = fmaxf(pm[r], __shfl_xor(pm[r], 1));
    pm[r] = fmaxf(pm[r], __shfl_xor(pm[r], 2));
    pm[r] = fmaxf(pm[r], __shfl_xor(pm[r], 4));
    pm[r] = fmaxf(pm[r], __shfl_xor(pm[r], 8));
  }
  float alpha[4];
#pragma unroll
  for (int r = 0; r < 4; ++r) {
    const float nm = fmaxf(m[r], pm[r]);
    alpha[r] = __expf(m[r] - nm);
    m[r] = nm;
  }
  float psum[4] = {0.f, 0.f, 0.f, 0.f};
#pragma unroll
  for (int nt = 0; nt < 4; ++nt)
#pragma unroll
    for (int r = 0; r < 4; ++r) {
      const float p = __expf(sc[nt][r] - m[r]);
      psum[r] += p;
      Pw[(lg * 4 + r) * 72 + nt * 16 + l15] = f2b(p);
    }
#pragma unroll
  for (int r = 0; r < 4; ++r) lsum[r] = lsum[r] * alpha[r] + psum[r];
#pragma unroll
  for (int dt = 0; dt < 8; ++dt)
#pragma unroll
    for (int r = 0; r < 4; ++r) acco[dt][r] *= alpha[r];
#pragma unroll
  for (int kk = 0; kk < 2; ++kk) {
    bf16x8 ap = *(const bf16x8*)(Pw + l15 * 72 + kk * 32 + lg * 8);
#pragma unroll
    for (int dt = 0; dt < 8; ++dt) {
      const int vrow = dt * 16 + l15;
      bf16x8 bv = *(const bf16x8*)(Vc + vrow * 64 +
                                   (((kk * 64 + lg * 16) ^ ((vrow & 7) << 4)) >> 1));
      acco[dt] = mfma16(ap, bv, acco[dt]);
    }
  }
}

__device__ __forceinline__ void attn_writeout(f32x4* acco, float* lsum,
                                              short* __restrict__ AO, int b, int qh,
                                              int q0, int l15, int lg) {
  float ls[4];
#pragma unroll
  for (int r = 0; r < 4; ++r) {
    float t = lsum[r];
    t += __shfl_xor(t, 1);
    t += __shfl_xor(t, 2);
    t += __shfl_xor(t, 4);
    t += __shfl_xor(t, 8);
    ls[r] = 1.0f / t;
  }
  short* ob = AO + (size_t)(b * S_LEN + q0) * (NQH * DK) + qh * DK;
#pragma unroll
  for (int dt = 0; dt < 8; ++dt)
#pragma unroll
    for (int r = 0; r < 4; ++r)
      ob[(size_t)(lg * 4 + r) * (NQH * DK) + dt * 16 + l15] = f2b(acco[dt][r] * ls[r]);
}

// grid: (16 q-tile pairs, 32 b*16+qh), block 256 (4 waves x 16 q-rows).
// Block x handles q-tiles qtA = x and qtB = 31-x  ->  33 tile-computations per block.
__global__ __launch_bounds__(256, 2) void attn_kernel(const short* __restrict__ Qr,
                                                      const short* __restrict__ Kr,
                                                      const short* __restrict__ Vt,
                                                      short* __restrict__ AO) {
  const int qtA = blockIdx.x;       // 0..15
  const int qtB = 31 - qtA;         // 16..31
  const int bh = blockIdx.y;
  const int b = bh >> 4, qh = bh & 15;
  const int kvh = qh >> 2;
  const short* Qb = Qr + (size_t)bh * S_LEN * DK;
  const short* Kb = Kr + (size_t)(b * NKVH + kvh) * S_LEN * DK;
  const short* Vb = Vt + (size_t)(b * NKVH + kvh) * DK * S_LEN;
  const int tid = threadIdx.x, lane = tid & 63, w = tid >> 6;
  const int l15 = lane & 15, lg = lane >> 4;

  __shared__ __align__(16) short KV[4][64 * 128];  // K0 V0 K1 V1, 16KB each
  __shared__ __align__(16) short P[4][16][72];     // per-wave P tile
  short* Pw = &P[w][0][0];

  const int q0A = qtA * 64 + w * 16, q0B = qtB * 64 + w * 16;
  bf16x8 aqA[4], aqB[4];
#pragma unroll
  for (int kk = 0; kk < 4; ++kk) {
    aqA[kk] = *(const bf16x8*)(Qb + (size_t)(q0A + l15) * DK + kk * 32 + lg * 8);
    aqB[kk] = *(const bf16x8*)(Qb + (size_t)(q0B + l15) * DK + kk * 32 + lg * 8);
  }

  f32x4 accoA[8] = {}, accoB[8] = {};
  float mA[4], lsA[4], mB[4], lsB[4];
#pragma unroll
  for (int r = 0; r < 4; ++r) { mA[r] = mB[r] = -1e30f; lsA[r] = lsB[r] = 0.f; }

  short* Kcur = KV[0]; short* Vcur = KV[1];
  short* Knxt = KV[2]; short* Vnxt = KV[3];

  stage_kv(Kb, Vb, 0, Kcur, Vcur, w, lane);
  asm volatile("s_waitcnt vmcnt(0)" ::: "memory");
  __syncthreads();

  for (int kt = 0; kt <= qtB; ++kt) {
    const int kb = kt * 64;
    if (kt < qtB) stage_kv(Kb, Vb, kb + 64, Knxt, Vnxt, w, lane);

    if (kt <= qtA) {  // both q-tiles active: share K/V fragment loads
      f32x4 scB[4] = {}, scA[4] = {};
#pragma unroll
      for (int kk = 0; kk < 4; ++kk)
#pragma unroll
        for (int nt = 0; nt < 4; ++nt) {
          const int krow = nt * 16 + l15;
          bf16x8 bk = *(const bf16x8*)(Kcur + krow * 128 +
                                       (((kk * 64 + lg * 16) ^ ((krow & 7) << 4)) >> 1));
          scB[nt] = mfma16(aqB[kk], bk, scB[nt]);
          scA[nt] = mfma16(aqA[kk], bk, scA[nt]);
        }
      sm_pv(scB, mB, lsB, accoB, Vcur, Pw, q0B, false, kb, l15, lg);
      sm_pv(scA, mA, lsA, accoA, Vcur, Pw, q0A, kt == qtA, kb, l15, lg);
    } else {
      f32x4 scB[4] = {};
#pragma unroll
      for (int kk = 0; kk < 4; ++kk)
#pragma unroll
        for (int nt = 0; nt < 4; ++nt) {
          const int krow = nt * 16 + l15;
          bf16x8 bk = *(const bf16x8*)(Kcur + krow * 128 +
                                       (((kk * 64 + lg * 16) ^ ((krow & 7) << 4)) >> 1));
          scB[nt] = mfma16(aqB[kk], bk, scB[nt]);
        }
      sm_pv(scB, mB, lsB, accoB, Vcur, Pw, q0B, kt == qtB, kb, l15, lg);
    }

    asm volatile("s_waitcnt vmcnt(0)" ::: "memory");
    __syncthreads();
    short* t;
    t = Kcur; Kcur = Knxt; Knxt = t;
    t = Vcur; Vcur = Vnxt; Vnxt = t;
  }

  attn_writeout(accoB, lsB, AO, b, qh, q0B, l15, lg);
  attn_writeout(accoA, lsA, AO, b, qh, q0A, l15, lg);
}

// ---------------------------------------------------------------- launch
extern "C" void kernel_launch(void* const* d_in, const int* in_sizes, int n_in,
                              void* d_out, int out_size, void* d_ws, size_t ws_size,
                              hipStream_t stream) {
  const float* x = (const float*)d_in[0];
  // d_in[1] = mask (causal tril) — implemented analytically
  const float* Wq = (const float*)d_in[2];
  const float* Wk = (const float*)d_in[3];
  const float* Wv = (const float*)d_in[4];
  const float* Wfc = (const float*)d_in[5];
  const float* qg = (const float*)d_in[6];
  const float* kg = (const float*)d_in[7];

  short* ws = (short*)d_ws;
  short* xb = ws;                                   // 4096*2048 (also reused as AO)
  short* WqT = xb + (size_t)4096 * 2048;            // 2048*2048
  short* WkT = WqT + (size_t)2048 * 2048;           // 512*2048
  short* WvT = WkT + (size_t)512 * 2048;            // 512*2048
  short* WfcT = WvT + (size_t)512 * 2048;           // 2048*2048
  short* Qr = WfcT + (size_t)2048 * 2048;           // 32*2048*128
  short* Kr = Qr + (size_t)32 * 2048 * 128;         // 8*2048*128
  short* Vt = Kr + (size_t)8 * 2048 * 128;          // 8*128*2048
  float* ropeT = (float*)(Vt + (size_t)8 * 128 * 2048);  // 2048*128 f32
  short* AO = xb;                                   // alias: x dead after V GEMM

  f32_to_bf16<<<(4096 * 2048 / 4 + 255) / 256, 256, 0, stream>>>(x, xb, 4096 * 2048 / 4);
  rope_table<<<(2048 * 64 + 255) / 256, 256, 0, stream>>>(ropeT);

  dim3 tb(32, 8);
  transpose_f2b<<<dim3(2048 / 32, 2048 / 32), tb, 0, stream>>>(Wq, WqT, 2048, 2048);
  transpose_f2b<<<dim3(512 / 32, 2048 / 32), tb, 0, stream>>>(Wk, WkT, 2048, 512);
  transpose_f2b<<<dim3(512 / 32, 2048 / 32), tb, 0, stream>>>(Wv, WvT, 2048, 512);
  transpose_f2b<<<dim3(2048 / 32, 2048 / 32), tb, 0, stream>>>(Wfc, WfcT, 2048, 2048);

  gemm_bt<1><<<dim3(32, 16), 256, 0, stream>>>(xb, WqT, Qr, nullptr, qg, ropeT, 4096, 2048, 2048);
  gemm_bt<2><<<dim3(32, 4), 256, 0, stream>>>(xb, WkT, Kr, nullptr, kg, ropeT, 4096, 512, 2048);
  gemm_bt<3><<<dim3(32, 4), 256, 0, stream>>>(xb, WvT, Vt, nullptr, nullptr, ropeT, 4096, 512, 2048);

  attn_kernel<<<dim3(16, 32), 256, 0, stream>>>(Qr, Kr, Vt, AO);

  gemm_bt<0><<<dim3(32, 16), 256, 0, stream>>>(AO, WfcT, nullptr, (float*)d_out, nullptr,
                                               ropeT, 4096, 2048, 2048);
}

// Round 4
// 278.917 us; speedup vs baseline: 2.4395x; 1.1584x over previous
//
#include <hip/hip_runtime.h>
#include <hip/hip_bf16.h>

typedef __attribute__((ext_vector_type(8))) short bf16x8;
typedef __attribute__((ext_vector_type(4))) short bf16x4;
typedef __attribute__((ext_vector_type(4))) float f32x4;

#define S_LEN 2048
#define DMODEL 2048
#define NQH 16
#define NKVH 4
#define DK 128

__device__ __forceinline__ float b2f(short u) {
  union { unsigned int i; float f; } x;
  x.i = ((unsigned int)(unsigned short)u) << 16;
  return x.f;
}
// round-to-nearest-even f32 -> bf16 (finite inputs only)
__device__ __forceinline__ short f2b(float f) {
  union { float f; unsigned int i; } x; x.f = f;
  unsigned int r = (x.i + 0x7fffu + ((x.i >> 16) & 1u)) >> 16;
  return (short)r;
}
__device__ __forceinline__ f32x4 mfma16(bf16x8 a, bf16x8 b, f32x4 c) {
  return __builtin_amdgcn_mfma_f32_16x16x32_bf16(a, b, c, 0, 0, 0);
}
__device__ __forceinline__ void async16(short* lds, const short* g) {
  __builtin_amdgcn_global_load_lds(
      (const __attribute__((address_space(1))) unsigned int*)(const void*)g,
      (__attribute__((address_space(3))) unsigned int*)(void*)lds, 16, 0, 0);
}

// ---------------------------------------------------------------- f32 -> bf16 convert
__global__ void f32_to_bf16(const float* __restrict__ in, short* __restrict__ out, int n4) {
  int i = blockIdx.x * blockDim.x + threadIdx.x;
  if (i >= n4) return;
  float4 v = ((const float4*)in)[i];
  bf16x4 o;
  o[0] = f2b(v.x); o[1] = f2b(v.y); o[2] = f2b(v.z); o[3] = f2b(v.w);
  ((bf16x4*)out)[i] = o;
}

// ---------------------------------------------------------------- RoPE cos/sin table
// rt[s*128 + d] = cos(s * base^(-d/64)), rt[s*128 + 64 + d] = sin(...)
__global__ void rope_table(float* __restrict__ rt) {
  int i = blockIdx.x * blockDim.x + threadIdx.x;  // 2048*64
  int s = i >> 6, d = i & 63;
  float ang = (float)s * __expf((float)d * -0.14391157f);  // ln(10000)/64
  float c, sn;
  __sincosf(ang, &sn, &c);
  rt[s * 128 + d] = c;
  rt[s * 128 + 64 + d] = sn;
}

// ---------------------------------------------------------------- transpose f32 -> bf16
__global__ void transpose_f2b(const float* __restrict__ in, short* __restrict__ out,
                              int R, int C) {
  __shared__ short t[32][33];
  int c0 = blockIdx.x * 32, r0 = blockIdx.y * 32;
  int tx = threadIdx.x, ty = threadIdx.y;  // block (32,8)
#pragma unroll
  for (int i = 0; i < 32; i += 8)
    t[ty + i][tx] = f2b(in[(size_t)(r0 + ty + i) * C + c0 + tx]);
  __syncthreads();
#pragma unroll
  for (int i = 0; i < 32; i += 8)
    out[(size_t)(c0 + ty + i) * R + r0 + tx] = t[tx][ty + i];
}

// ---------------------------------------------------------------- fused QKV GEMM
// A row-major 4096x2048 bf16 (x), WT row-major 3072x2048 bf16 ([WqT;WkT;WvT]).
// 1-D grid 768 blocks, XCD-swizzled. nb<16: Q head nb (RoPE+RMS+gamma+1/sqrt(dk));
// nb in [16,20): K head nb-16 (RoPE+RMS+gamma); nb in [20,24): V head nb-20 (transpose).
__global__ __launch_bounds__(256) void gemm_qkv(const short* __restrict__ A,
                                                const short* __restrict__ WT,
                                                short* __restrict__ Qr,
                                                short* __restrict__ Kr,
                                                short* __restrict__ Vtr,
                                                const float* __restrict__ qg,
                                                const float* __restrict__ kg,
                                                const float* __restrict__ ropeT) {
  constexpr int CS_LD = 136;
  __shared__ __align__(16) short smem[128 * CS_LD];  // 34.8 KB (epilogue); main uses 16 KB
  short* As = smem;
  short* Bs = smem + 128 * 32;

  const int flat = blockIdx.x;
  const int nw = (flat & 7) * 96 + (flat >> 3);  // bijective XCD swizzle (768 = 8*96)
  const int mb = nw & 31;
  const int nb = nw >> 5;

  const int tid = threadIdx.x;
  const int lane = tid & 63;
  const int w = tid >> 6;
  const int wm = w >> 1, wn = w & 1;
  const int l15 = lane & 15, lg = lane >> 4;
  const int K = DMODEL;

  f32x4 acc[4][4] = {};
  const short* Ab = A + (size_t)mb * 128 * K;
  const short* Bb = WT + (size_t)nb * 128 * K;

  for (int k0 = 0; k0 < K; k0 += 32) {
    __syncthreads();
    {
      const int rb0 = w * 32;
      const int rb1 = w * 32 + 16;
      const int mr = lane >> 2;
      const int kg2 = (lane & 3) * 8;
      async16(As + rb0 * 32, Ab + (size_t)(rb0 + mr) * K + k0 + kg2);
      async16(As + rb1 * 32, Ab + (size_t)(rb1 + mr) * K + k0 + kg2);
      async16(Bs + rb0 * 32, Bb + (size_t)(rb0 + mr) * K + k0 + kg2);
      async16(Bs + rb1 * 32, Bb + (size_t)(rb1 + mr) * K + k0 + kg2);
    }
    __syncthreads();
    bf16x8 af[4], bfr[4];
#pragma unroll
    for (int mt = 0; mt < 4; ++mt)
      af[mt] = *(const bf16x8*)(As + (wm * 64 + mt * 16 + l15) * 32 + lg * 8);
#pragma unroll
    for (int nt = 0; nt < 4; ++nt)
      bfr[nt] = *(const bf16x8*)(Bs + (wn * 64 + nt * 16 + l15) * 32 + lg * 8);
    __builtin_amdgcn_s_setprio(1);
#pragma unroll
    for (int mt = 0; mt < 4; ++mt)
#pragma unroll
      for (int nt = 0; nt < 4; ++nt)
        acc[mt][nt] = mfma16(af[mt], bfr[nt], acc[mt][nt]);
    __builtin_amdgcn_s_setprio(0);
  }

  // ---- stage C tile (bf16) to LDS ----
  __syncthreads();
  short* Cs = smem;
#pragma unroll
  for (int mt = 0; mt < 4; ++mt)
#pragma unroll
    for (int nt = 0; nt < 4; ++nt)
#pragma unroll
      for (int r = 0; r < 4; ++r)
        Cs[(wm * 64 + mt * 16 + lg * 4 + r) * CS_LD + wn * 64 + nt * 16 + l15] =
            f2b(acc[mt][nt][r]);
  __syncthreads();

  const int srow0 = mb * 128;
  const int b = srow0 >> 11;

  if (nb < 20) {  // ---- Q/K: vectorized RoPE + RMSNorm + gamma ----
    const bool isQ = nb < 16;
    const int h = isQ ? nb : nb - 16;
    const float* gamma = isQ ? qg : kg;
    const int r = tid >> 1, half = tid & 1;
    const int s = (srow0 + r) & 2047;
    const float* rt = ropeT + (size_t)s * 128;
    float ss = 0.f;
    bf16x8 ov[8];
#pragma unroll
    for (int j = 0; j < 8; ++j) {
      bf16x8 t1v = *(const bf16x8*)(Cs + r * CS_LD + j * 8);
      bf16x8 t2v = *(const bf16x8*)(Cs + r * CS_LD + 64 + j * 8);
      float4 c0 = *(const float4*)(rt + j * 8);
      float4 c1 = *(const float4*)(rt + j * 8 + 4);
      float4 s0 = *(const float4*)(rt + 64 + j * 8);
      float4 s1 = *(const float4*)(rt + 64 + j * 8 + 4);
      float cc[8] = {c0.x, c0.y, c0.z, c0.w, c1.x, c1.y, c1.z, c1.w};
      float sn[8] = {s0.x, s0.y, s0.z, s0.w, s1.x, s1.y, s1.z, s1.w};
#pragma unroll
      for (int i = 0; i < 8; ++i) {
        float t1 = b2f(t1v[i]), t2 = b2f(t2v[i]);
        float o = half ? (t2 * cc[i] + t1 * sn[i]) : (t1 * cc[i] - t2 * sn[i]);
        ss += o * o;
        ov[j][i] = f2b(o);
      }
    }
    ss += __shfl_xor(ss, 1);
    float inv = rsqrtf(ss * (1.0f / 128.0f) + 1e-6f);
    if (isQ) inv *= 0.08838834764831845f;  // fold softmax 1/sqrt(DK)
    const int NH = isQ ? NQH : NKVH;
    short* outp = isQ ? Qr : Kr;
    short* ob = outp + ((size_t)(b * NH + h) * S_LEN + s) * DK + half * 64;
#pragma unroll
    for (int j = 0; j < 8; ++j) {
      float4 g0 = *(const float4*)(gamma + half * 64 + j * 8);
      float4 g1 = *(const float4*)(gamma + half * 64 + j * 8 + 4);
      float gg[8] = {g0.x, g0.y, g0.z, g0.w, g1.x, g1.y, g1.z, g1.w};
      bf16x8 vv;
#pragma unroll
      for (int i = 0; i < 8; ++i) vv[i] = f2b(b2f(ov[j][i]) * inv * gg[i]);
      *(bf16x8*)(ob + j * 8) = vv;
    }
  } else {  // ---- V: transpose -> Vt[(b*4+h)][d][s] ----
    const int h = nb - 20;
    const int d = tid & 127;
    const int sh = tid >> 7;
    const int sbase = (srow0 & 2047) + sh * 64;
    short* ob = Vtr + ((size_t)(b * NKVH + h) * DK + d) * S_LEN + sbase;
    for (int i0 = 0; i0 < 64; i0 += 8) {
      bf16x8 v;
#pragma unroll
      for (int j = 0; j < 8; ++j) v[j] = Cs[(sh * 64 + i0 + j) * CS_LD + d];
      *(bf16x8*)(ob + i0) = v;
    }
  }
}

// ---------------------------------------------------------------- out GEMM (AO @ WfcT -> f32)
__global__ __launch_bounds__(256) void gemm_out(const short* __restrict__ A,
                                                const short* __restrict__ BT,
                                                float* __restrict__ outf) {
  __shared__ __align__(16) short smem[128 * 32 * 2];
  short* As = smem;
  short* Bs = smem + 128 * 32;

  const int flat = blockIdx.x;
  const int nw = (flat & 7) * 64 + (flat >> 3);  // 512 = 8*64
  const int mb = nw & 31;
  const int nb = nw >> 5;

  const int tid = threadIdx.x;
  const int lane = tid & 63;
  const int w = tid >> 6;
  const int wm = w >> 1, wn = w & 1;
  const int l15 = lane & 15, lg = lane >> 4;
  const int K = NQH * DK, N = DMODEL;

  f32x4 acc[4][4] = {};
  const short* Ab = A + (size_t)mb * 128 * K;
  const short* Bb = BT + (size_t)nb * 128 * K;

  for (int k0 = 0; k0 < K; k0 += 32) {
    __syncthreads();
    {
      const int rb0 = w * 32;
      const int rb1 = w * 32 + 16;
      const int mr = lane >> 2;
      const int kg2 = (lane & 3) * 8;
      async16(As + rb0 * 32, Ab + (size_t)(rb0 + mr) * K + k0 + kg2);
      async16(As + rb1 * 32, Ab + (size_t)(rb1 + mr) * K + k0 + kg2);
      async16(Bs + rb0 * 32, Bb + (size_t)(rb0 + mr) * K + k0 + kg2);
      async16(Bs + rb1 * 32, Bb + (size_t)(rb1 + mr) * K + k0 + kg2);
    }
    __syncthreads();
    bf16x8 af[4], bfr[4];
#pragma unroll
    for (int mt = 0; mt < 4; ++mt)
      af[mt] = *(const bf16x8*)(As + (wm * 64 + mt * 16 + l15) * 32 + lg * 8);
#pragma unroll
    for (int nt = 0; nt < 4; ++nt)
      bfr[nt] = *(const bf16x8*)(Bs + (wn * 64 + nt * 16 + l15) * 32 + lg * 8);
    __builtin_amdgcn_s_setprio(1);
#pragma unroll
    for (int mt = 0; mt < 4; ++mt)
#pragma unroll
      for (int nt = 0; nt < 4; ++nt)
        acc[mt][nt] = mfma16(af[mt], bfr[nt], acc[mt][nt]);
    __builtin_amdgcn_s_setprio(0);
  }

#pragma unroll
  for (int mt = 0; mt < 4; ++mt) {
    const int row = mb * 128 + wm * 64 + mt * 16 + lg * 4;
#pragma unroll
    for (int nt = 0; nt < 4; ++nt) {
      const int col = nb * 128 + wn * 64 + nt * 16 + l15;
#pragma unroll
      for (int r = 0; r < 4; ++r)
        outf[(size_t)(row + r) * N + col] = acc[mt][nt][r];
    }
  }
}

// ---------------------------------------------------------------- flash attention
__device__ __forceinline__ void stage_kv(const short* __restrict__ Kb,
                                         const short* __restrict__ Vb, int kb,
                                         short* Ks, short* Vs, int w, int lane) {
#pragma unroll
  for (int i = 0; i < 4; ++i) {
    const int c = 4 * w + i;
    const int krow = c * 4 + (lane >> 4);
    const int kcol = (((lane & 15) * 16) ^ ((krow & 7) << 4)) >> 1;
    async16(Ks + c * 512, Kb + (size_t)(kb + krow) * DK + kcol);
    const int vrow = c * 8 + (lane >> 3);
    const int vcol = (((lane & 7) * 16) ^ ((vrow & 7) << 4)) >> 1;
    async16(Vs + c * 512, Vb + (size_t)vrow * S_LEN + kb + vcol);
  }
}

__device__ __forceinline__ void sm_pv(f32x4* sc, float* m, float* lsum, f32x4* acco,
                                      const short* Vc, short* Pw, int q0, bool diag,
                                      int kb, int l15, int lg) {
  if (diag) {
#pragma unroll
    for (int nt = 0; nt < 4; ++nt) {
      const int k = kb + nt * 16 + l15;
#pragma unroll
      for (int r = 0; r < 4; ++r)
        if (k > q0 + lg * 4 + r) sc[nt][r] = -1e30f;
    }
  }
  float pm[4];
#pragma unroll
  for (int r = 0; r < 4; ++r)
    pm[r] = fmaxf(fmaxf(sc[0][r], sc[1][r]), fmaxf(sc[2][r], sc[3][r]));
#pragma unroll
  for (int r = 0; r < 4; ++r) {
    pm[r] = fmaxf(pm[r], __shfl_xor(pm[r], 1));
    pm[r] = fmaxf(pm[r], __shfl_xor(pm[r], 2));
    pm[r] = fmaxf(pm[r], __shfl_xor(pm[r], 4));
    pm[r] = fmaxf(pm[r], __shfl_xor(pm[r], 8));
  }
  // defer-max (T13): only rescale when the max moved by > 8
  float need = -1e30f;
#pragma unroll
  for (int r = 0; r < 4; ++r) need = fmaxf(need, pm[r] - m[r]);
  if (__any(need > 8.f)) {
#pragma unroll
    for (int r = 0; r < 4; ++r) {
      const float nm = fmaxf(m[r], pm[r]);
      const float alpha = __expf(m[r] - nm);
      m[r] = nm;
      lsum[r] *= alpha;
#pragma unroll
      for (int dt = 0; dt < 8; ++dt) acco[dt][r] *= alpha;
    }
  }
  float psum[4] = {0.f, 0.f, 0.f, 0.f};
#pragma unroll
  for (int nt = 0; nt < 4; ++nt)
#pragma unroll
    for (int r = 0; r < 4; ++r) {
      const float p = __expf(sc[nt][r] - m[r]);
      psum[r] += p;
      Pw[(lg * 4 + r) * 72 + nt * 16 + l15] = f2b(p);
    }
#pragma unroll
  for (int r = 0; r < 4; ++r) lsum[r] += psum[r];
#pragma unroll
  for (int kk = 0; kk < 2; ++kk) {
    bf16x8 ap = *(const bf16x8*)(Pw + l15 * 72 + kk * 32 + lg * 8);
    __builtin_amdgcn_s_setprio(1);
#pragma unroll
    for (int dt = 0; dt < 8; ++dt) {
      const int vrow = dt * 16 + l15;
      bf16x8 bv = *(const bf16x8*)(Vc + vrow * 64 +
                                   (((kk * 64 + lg * 16) ^ ((vrow & 7) << 4)) >> 1));
      acco[dt] = mfma16(ap, bv, acco[dt]);
    }
    __builtin_amdgcn_s_setprio(0);
  }
}

__device__ __forceinline__ void attn_writeout(f32x4* acco, float* lsum,
                                              short* __restrict__ AO, int b, int qh,
                                              int q0, int l15, int lg) {
  float ls[4];
#pragma unroll
  for (int r = 0; r < 4; ++r) {
    float t = lsum[r];
    t += __shfl_xor(t, 1);
    t += __shfl_xor(t, 2);
    t += __shfl_xor(t, 4);
    t += __shfl_xor(t, 8);
    ls[r] = 1.0f / t;
  }
  short* ob = AO + (size_t)(b * S_LEN + q0) * (NQH * DK) + qh * DK;
#pragma unroll
  for (int dt = 0; dt < 8; ++dt)
#pragma unroll
    for (int r = 0; r < 4; ++r)
      ob[(size_t)(lg * 4 + r) * (NQH * DK) + dt * 16 + l15] = f2b(acco[dt][r] * ls[r]);
}

// 1-D grid 512 blocks XCD-swizzled: x = q-tile pair (0..15), bh = b*16+qh (0..31).
// Block handles q-tiles qtA = x and qtB = 31-x -> 33 tile-computations each.
__global__ __launch_bounds__(256, 2) void attn_kernel(const short* __restrict__ Qr,
                                                      const short* __restrict__ Kr,
                                                      const short* __restrict__ Vt,
                                                      short* __restrict__ AO) {
  const int flat = blockIdx.x;
  const int nw = (flat & 7) * 64 + (flat >> 3);  // 512 = 8*64: 4 bh (1 KV group) per XCD
  const int qtA = nw & 15;
  const int bh = nw >> 4;
  const int qtB = 31 - qtA;
  const int b = bh >> 4, qh = bh & 15;
  const int kvh = qh >> 2;
  const short* Qb = Qr + (size_t)bh * S_LEN * DK;
  const short* Kb = Kr + (size_t)(b * NKVH + kvh) * S_LEN * DK;
  const short* Vb = Vt + (size_t)(b * NKVH + kvh) * DK * S_LEN;
  const int tid = threadIdx.x, lane = tid & 63, w = tid >> 6;
  const int l15 = lane & 15, lg = lane >> 4;

  __shared__ __align__(16) short KV[4][64 * 128];
  __shared__ __align__(16) short P[4][16][72];
  short* Pw = &P[w][0][0];

  const int q0A = qtA * 64 + w * 16, q0B = qtB * 64 + w * 16;
  bf16x8 aqA[4], aqB[4];
#pragma unroll
  for (int kk = 0; kk < 4; ++kk) {
    aqA[kk] = *(const bf16x8*)(Qb + (size_t)(q0A + l15) * DK + kk * 32 + lg * 8);
    aqB[kk] = *(const bf16x8*)(Qb + (size_t)(q0B + l15) * DK + kk * 32 + lg * 8);
  }

  f32x4 accoA[8] = {}, accoB[8] = {};
  float mA[4], lsA[4], mB[4], lsB[4];
#pragma unroll
  for (int r = 0; r < 4; ++r) { mA[r] = mB[r] = -1e30f; lsA[r] = lsB[r] = 0.f; }

  short* Kcur = KV[0]; short* Vcur = KV[1];
  short* Knxt = KV[2]; short* Vnxt = KV[3];

  stage_kv(Kb, Vb, 0, Kcur, Vcur, w, lane);
  asm volatile("s_waitcnt vmcnt(0)" ::: "memory");
  __syncthreads();

  for (int kt = 0; kt <= qtB; ++kt) {
    const int kb = kt * 64;
    if (kt < qtB) stage_kv(Kb, Vb, kb + 64, Knxt, Vnxt, w, lane);

    if (kt <= qtA) {
      f32x4 scB[4] = {}, scA[4] = {};
      __builtin_amdgcn_s_setprio(1);
#pragma unroll
      for (int kk = 0; kk < 4; ++kk)
#pragma unroll
        for (int nt = 0; nt < 4; ++nt) {
          const int krow = nt * 16 + l15;
          bf16x8 bk = *(const bf16x8*)(Kcur + krow * 128 +
                                       (((kk * 64 + lg * 16) ^ ((krow & 7) << 4)) >> 1));
          scB[nt] = mfma16(aqB[kk], bk, scB[nt]);
          scA[nt] = mfma16(aqA[kk], bk, scA[nt]);
        }
      __builtin_amdgcn_s_setprio(0);
      sm_pv(scB, mB, lsB, accoB, Vcur, Pw, q0B, false, kb, l15, lg);
      sm_pv(scA, mA, lsA, accoA, Vcur, Pw, q0A, kt == qtA, kb, l15, lg);
    } else {
      f32x4 scB[4] = {};
      __builtin_amdgcn_s_setprio(1);
#pragma unroll
      for (int kk = 0; kk < 4; ++kk)
#pragma unroll
        for (int nt = 0; nt < 4; ++nt) {
          const int krow = nt * 16 + l15;
          bf16x8 bk = *(const bf16x8*)(Kcur + krow * 128 +
                                       (((kk * 64 + lg * 16) ^ ((krow & 7) << 4)) >> 1));
          scB[nt] = mfma16(aqB[kk], bk, scB[nt]);
        }
      __builtin_amdgcn_s_setprio(0);
      sm_pv(scB, mB, lsB, accoB, Vcur, Pw, q0B, kt == qtB, kb, l15, lg);
    }

    asm volatile("s_waitcnt vmcnt(0)" ::: "memory");
    __syncthreads();
    short* t;
    t = Kcur; Kcur = Knxt; Knxt = t;
    t = Vcur; Vcur = Vnxt; Vnxt = t;
  }

  attn_writeout(accoB, lsB, AO, b, qh, q0B, l15, lg);
  attn_writeout(accoA, lsA, AO, b, qh, q0A, l15, lg);
}

// ---------------------------------------------------------------- launch
extern "C" void kernel_launch(void* const* d_in, const int* in_sizes, int n_in,
                              void* d_out, int out_size, void* d_ws, size_t ws_size,
                              hipStream_t stream) {
  const float* x = (const float*)d_in[0];
  // d_in[1] = mask (causal tril) — implemented analytically
  const float* Wq = (const float*)d_in[2];
  const float* Wk = (const float*)d_in[3];
  const float* Wv = (const float*)d_in[4];
  const float* Wfc = (const float*)d_in[5];
  const float* qg = (const float*)d_in[6];
  const float* kg = (const float*)d_in[7];

  short* ws = (short*)d_ws;
  short* xb = ws;                                   // 4096*2048 (also reused as AO)
  short* WqkvT = xb + (size_t)4096 * 2048;          // 3072*2048 = [WqT;WkT;WvT]
  short* WqT = WqkvT;
  short* WkT = WqT + (size_t)2048 * 2048;
  short* WvT = WkT + (size_t)512 * 2048;
  short* WfcT = WvT + (size_t)512 * 2048;           // 2048*2048
  short* Qr = WfcT + (size_t)2048 * 2048;           // 32*2048*128
  short* Kr = Qr + (size_t)32 * 2048 * 128;         // 8*2048*128
  short* Vt = Kr + (size_t)8 * 2048 * 128;          // 8*128*2048
  float* ropeT = (float*)(Vt + (size_t)8 * 128 * 2048);  // 2048*128 f32
  short* AO = xb;                                   // alias: x dead after QKV GEMM

  f32_to_bf16<<<(4096 * 2048 / 4 + 255) / 256, 256, 0, stream>>>(x, xb, 4096 * 2048 / 4);
  rope_table<<<(2048 * 64 + 255) / 256, 256, 0, stream>>>(ropeT);

  dim3 tb(32, 8);
  transpose_f2b<<<dim3(2048 / 32, 2048 / 32), tb, 0, stream>>>(Wq, WqT, 2048, 2048);
  transpose_f2b<<<dim3(512 / 32, 2048 / 32), tb, 0, stream>>>(Wk, WkT, 2048, 512);
  transpose_f2b<<<dim3(512 / 32, 2048 / 32), tb, 0, stream>>>(Wv, WvT, 2048, 512);
  transpose_f2b<<<dim3(2048 / 32, 2048 / 32), tb, 0, stream>>>(Wfc, WfcT, 2048, 2048);

  gemm_qkv<<<768, 256, 0, stream>>>(xb, WqkvT, Qr, Kr, Vt, qg, kg, ropeT);

  attn_kernel<<<512, 256, 0, stream>>>(Qr, Kr, Vt, AO);

  gemm_out<<<512, 256, 0, stream>>>(AO, WfcT, (float*)d_out);
}

// Round 5
// 259.247 us; speedup vs baseline: 2.6246x; 1.0759x over previous
//
#include <hip/hip_runtime.h>
#include <hip/hip_bf16.h>

typedef __attribute__((ext_vector_type(8))) short bf16x8;
typedef __attribute__((ext_vector_type(4))) short bf16x4;
typedef __attribute__((ext_vector_type(4))) float f32x4;

#define S_LEN 2048
#define DMODEL 2048
#define NQH 16
#define NKVH 4
#define DK 128

__device__ __forceinline__ float b2f(short u) {
  union { unsigned int i; float f; } x;
  x.i = ((unsigned int)(unsigned short)u) << 16;
  return x.f;
}
// round-to-nearest-even f32 -> bf16 (finite inputs only)
__device__ __forceinline__ short f2b(float f) {
  union { float f; unsigned int i; } x; x.f = f;
  unsigned int r = (x.i + 0x7fffu + ((x.i >> 16) & 1u)) >> 16;
  return (short)r;
}
__device__ __forceinline__ f32x4 mfma16(bf16x8 a, bf16x8 b, f32x4 c) {
  return __builtin_amdgcn_mfma_f32_16x16x32_bf16(a, b, c, 0, 0, 0);
}
__device__ __forceinline__ void async16(short* lds, const short* g) {
  __builtin_amdgcn_global_load_lds(
      (const __attribute__((address_space(1))) unsigned int*)(const void*)g,
      (__attribute__((address_space(3))) unsigned int*)(void*)lds, 16, 0, 0);
}

// ---------------------------------------------------------------- f32 -> bf16 convert
__global__ void f32_to_bf16(const float* __restrict__ in, short* __restrict__ out, int n4) {
  int i = blockIdx.x * blockDim.x + threadIdx.x;
  if (i >= n4) return;
  float4 v = ((const float4*)in)[i];
  bf16x4 o;
  o[0] = f2b(v.x); o[1] = f2b(v.y); o[2] = f2b(v.z); o[3] = f2b(v.w);
  ((bf16x4*)out)[i] = o;
}

// ---------------------------------------------------------------- RoPE cos/sin table
__global__ void rope_table(float* __restrict__ rt) {
  int i = blockIdx.x * blockDim.x + threadIdx.x;  // 2048*64
  int s = i >> 6, d = i & 63;
  float ang = (float)s * __expf((float)d * -0.14391157f);  // ln(10000)/64
  float c, sn;
  __sincosf(ang, &sn, &c);
  rt[s * 128 + d] = c;
  rt[s * 128 + 64 + d] = sn;
}

// ---------------------------------------------------------------- transpose f32 -> bf16
__global__ void transpose_f2b(const float* __restrict__ in, short* __restrict__ out,
                              int R, int C) {
  __shared__ short t[32][33];
  int c0 = blockIdx.x * 32, r0 = blockIdx.y * 32;
  int tx = threadIdx.x, ty = threadIdx.y;  // block (32,8)
#pragma unroll
  for (int i = 0; i < 32; i += 8)
    t[ty + i][tx] = f2b(in[(size_t)(r0 + ty + i) * C + c0 + tx]);
  __syncthreads();
#pragma unroll
  for (int i = 0; i < 32; i += 8)
    out[(size_t)(c0 + ty + i) * R + r0 + tx] = t[tx][ty + i];
}

// ---------------------------------------------------------------- GEMM staging
// Stage a [128 rows][64 cols] bf16 tile (16KB), XOR-swizzled: the element at LDS
// linear position (row, c) is global (row, c ^ ((row&7)*8)). gload_lds writes
// linearly (wave-uniform base + lane*16B); swizzle applied on the global SOURCE.
// Wave w stages rows [w*32, w*32+32) in 4 x 1KB loads.
__device__ __forceinline__ void stage_tile64(short* Ls, const short* Gb, int ldg,
                                             int w, int lane) {
#pragma unroll
  for (int i = 0; i < 4; ++i) {
    const int r0 = w * 32 + i * 8;
    const int row = r0 + (lane >> 3);
    const int colb = ((lane & 7) * 8) ^ ((row & 7) << 3);  // shorts
    async16(Ls + r0 * 64, Gb + (size_t)row * ldg + colb);
  }
}

// ---------------------------------------------------------------- fused QKV GEMM
// A row-major 4096x2048 bf16 (x), WT row-major 3072x2048 bf16 ([WqT;WkT;WvT]).
// 1-D grid 768 blocks, XCD-swizzled. nb<16: Q head nb (RoPE+RMS+gamma+1/sqrt(dk));
// nb in [16,20): K head nb-16; nb in [20,24): V head nb-20 (transpose).
__global__ __launch_bounds__(256) void gemm_qkv(const short* __restrict__ A,
                                                const short* __restrict__ WT,
                                                short* __restrict__ Qr,
                                                short* __restrict__ Kr,
                                                short* __restrict__ Vtr,
                                                const float* __restrict__ qg,
                                                const float* __restrict__ kg,
                                                const float* __restrict__ ropeT) {
  constexpr int CS_LD = 136;
  __shared__ __align__(16) short smem[128 * CS_LD];  // epilogue 34.8KB; main 32KB
  short* As = smem;
  short* Bs = smem + 128 * 64;

  const int flat = blockIdx.x;
  const int nw = (flat & 7) * 96 + (flat >> 3);  // bijective XCD swizzle (768 = 8*96)
  const int mb = nw & 31;
  const int nb = nw >> 5;

  const int tid = threadIdx.x;
  const int lane = tid & 63;
  const int w = tid >> 6;
  const int wm = w >> 1, wn = w & 1;
  const int l15 = lane & 15, lg = lane >> 4;
  const int K = DMODEL;

  f32x4 acc[4][4] = {};
  const short* Ab = A + (size_t)mb * 128 * K;
  const short* Bb = WT + (size_t)nb * 128 * K;

  for (int k0 = 0; k0 < K; k0 += 64) {
    __syncthreads();
    stage_tile64(As, Ab + k0, K, w, lane);
    stage_tile64(Bs, Bb + k0, K, w, lane);
    __syncthreads();
#pragma unroll
    for (int kk = 0; kk < 2; ++kk) {
      bf16x8 af[4], bfr[4];
#pragma unroll
      for (int mt = 0; mt < 4; ++mt)
        af[mt] = *(const bf16x8*)(As + (wm * 64 + mt * 16 + l15) * 64 +
                                  ((kk * 32 + lg * 8) ^ ((l15 & 7) << 3)));
#pragma unroll
      for (int nt = 0; nt < 4; ++nt)
        bfr[nt] = *(const bf16x8*)(Bs + (wn * 64 + nt * 16 + l15) * 64 +
                                   ((kk * 32 + lg * 8) ^ ((l15 & 7) << 3)));
#pragma unroll
      for (int mt = 0; mt < 4; ++mt)
#pragma unroll
        for (int nt = 0; nt < 4; ++nt)
          acc[mt][nt] = mfma16(af[mt], bfr[nt], acc[mt][nt]);
    }
  }

  // ---- stage C tile (bf16) to LDS ----
  __syncthreads();
  short* Cs = smem;
#pragma unroll
  for (int mt = 0; mt < 4; ++mt)
#pragma unroll
    for (int nt = 0; nt < 4; ++nt)
#pragma unroll
      for (int r = 0; r < 4; ++r)
        Cs[(wm * 64 + mt * 16 + lg * 4 + r) * CS_LD + wn * 64 + nt * 16 + l15] =
            f2b(acc[mt][nt][r]);
  __syncthreads();

  const int srow0 = mb * 128;
  const int b = srow0 >> 11;

  if (nb < 20) {  // ---- Q/K: vectorized RoPE + RMSNorm + gamma ----
    const bool isQ = nb < 16;
    const int h = isQ ? nb : nb - 16;
    const float* gamma = isQ ? qg : kg;
    const int r = tid >> 1, half = tid & 1;
    const int s = (srow0 + r) & 2047;
    const float* rt = ropeT + (size_t)s * 128;
    float ss = 0.f;
    bf16x8 ov[8];
#pragma unroll
    for (int j = 0; j < 8; ++j) {
      bf16x8 t1v = *(const bf16x8*)(Cs + r * CS_LD + j * 8);
      bf16x8 t2v = *(const bf16x8*)(Cs + r * CS_LD + 64 + j * 8);
      float4 c0 = *(const float4*)(rt + j * 8);
      float4 c1 = *(const float4*)(rt + j * 8 + 4);
      float4 s0 = *(const float4*)(rt + 64 + j * 8);
      float4 s1 = *(const float4*)(rt + 64 + j * 8 + 4);
      float cc[8] = {c0.x, c0.y, c0.z, c0.w, c1.x, c1.y, c1.z, c1.w};
      float sn[8] = {s0.x, s0.y, s0.z, s0.w, s1.x, s1.y, s1.z, s1.w};
#pragma unroll
      for (int i = 0; i < 8; ++i) {
        float t1 = b2f(t1v[i]), t2 = b2f(t2v[i]);
        float o = half ? (t2 * cc[i] + t1 * sn[i]) : (t1 * cc[i] - t2 * sn[i]);
        ss += o * o;
        ov[j][i] = f2b(o);
      }
    }
    ss += __shfl_xor(ss, 1);
    float inv = rsqrtf(ss * (1.0f / 128.0f) + 1e-6f);
    if (isQ) inv *= 0.08838834764831845f;  // fold softmax 1/sqrt(DK)
    const int NH = isQ ? NQH : NKVH;
    short* outp = isQ ? Qr : Kr;
    short* ob = outp + ((size_t)(b * NH + h) * S_LEN + s) * DK + half * 64;
#pragma unroll
    for (int j = 0; j < 8; ++j) {
      float4 g0 = *(const float4*)(gamma + half * 64 + j * 8);
      float4 g1 = *(const float4*)(gamma + half * 64 + j * 8 + 4);
      float gg[8] = {g0.x, g0.y, g0.z, g0.w, g1.x, g1.y, g1.z, g1.w};
      bf16x8 vv;
#pragma unroll
      for (int i = 0; i < 8; ++i) vv[i] = f2b(b2f(ov[j][i]) * inv * gg[i]);
      *(bf16x8*)(ob + j * 8) = vv;
    }
  } else {  // ---- V: transpose -> Vt[(b*4+h)][d][s] ----
    const int h = nb - 20;
    const int d = tid & 127;
    const int sh = tid >> 7;
    const int sbase = (srow0 & 2047) + sh * 64;
    short* ob = Vtr + ((size_t)(b * NKVH + h) * DK + d) * S_LEN + sbase;
    for (int i0 = 0; i0 < 64; i0 += 8) {
      bf16x8 v;
#pragma unroll
      for (int j = 0; j < 8; ++j) v[j] = Cs[(sh * 64 + i0 + j) * CS_LD + d];
      *(bf16x8*)(ob + i0) = v;
    }
  }
}

// ---------------------------------------------------------------- out GEMM (AO @ WfcT -> f32)
__global__ __launch_bounds__(256) void gemm_out(const short* __restrict__ A,
                                                const short* __restrict__ BT,
                                                float* __restrict__ outf) {
  __shared__ __align__(16) short smem[128 * 64 * 2];
  short* As = smem;
  short* Bs = smem + 128 * 64;

  const int flat = blockIdx.x;
  const int nw = (flat & 7) * 64 + (flat >> 3);  // 512 = 8*64
  const int mb = nw & 31;
  const int nb = nw >> 5;

  const int tid = threadIdx.x;
  const int lane = tid & 63;
  const int w = tid >> 6;
  const int wm = w >> 1, wn = w & 1;
  const int l15 = lane & 15, lg = lane >> 4;
  const int K = NQH * DK, N = DMODEL;

  f32x4 acc[4][4] = {};
  const short* Ab = A + (size_t)mb * 128 * K;
  const short* Bb = BT + (size_t)nb * 128 * K;

  for (int k0 = 0; k0 < K; k0 += 64) {
    __syncthreads();
    stage_tile64(As, Ab + k0, K, w, lane);
    stage_tile64(Bs, Bb + k0, K, w, lane);
    __syncthreads();
#pragma unroll
    for (int kk = 0; kk < 2; ++kk) {
      bf16x8 af[4], bfr[4];
#pragma unroll
      for (int mt = 0; mt < 4; ++mt)
        af[mt] = *(const bf16x8*)(As + (wm * 64 + mt * 16 + l15) * 64 +
                                  ((kk * 32 + lg * 8) ^ ((l15 & 7) << 3)));
#pragma unroll
      for (int nt = 0; nt < 4; ++nt)
        bfr[nt] = *(const bf16x8*)(Bs + (wn * 64 + nt * 16 + l15) * 64 +
                                   ((kk * 32 + lg * 8) ^ ((l15 & 7) << 3)));
#pragma unroll
      for (int mt = 0; mt < 4; ++mt)
#pragma unroll
        for (int nt = 0; nt < 4; ++nt)
          acc[mt][nt] = mfma16(af[mt], bfr[nt], acc[mt][nt]);
    }
  }

#pragma unroll
  for (int mt = 0; mt < 4; ++mt) {
    const int row = mb * 128 + wm * 64 + mt * 16 + lg * 4;
#pragma unroll
    for (int nt = 0; nt < 4; ++nt) {
      const int col = nb * 128 + wn * 64 + nt * 16 + l15;
#pragma unroll
      for (int r = 0; r < 4; ++r)
        outf[(size_t)(row + r) * N + col] = acc[mt][nt][r];
    }
  }
}

// ---------------------------------------------------------------- flash attention
__device__ __forceinline__ void stage_kv(const short* __restrict__ Kb,
                                         const short* __restrict__ Vb, int kb,
                                         short* Ks, short* Vs, int w, int lane) {
#pragma unroll
  for (int i = 0; i < 4; ++i) {
    const int c = 4 * w + i;
    const int krow = c * 4 + (lane >> 4);
    const int kcol = (((lane & 15) * 16) ^ ((krow & 7) << 4)) >> 1;
    async16(Ks + c * 512, Kb + (size_t)(kb + krow) * DK + kcol);
    const int vrow = c * 8 + (lane >> 3);
    const int vcol = (((lane & 7) * 16) ^ ((vrow & 7) << 4)) >> 1;
    async16(Vs + c * 512, Vb + (size_t)vrow * S_LEN + kb + vcol);
  }
}

__device__ __forceinline__ void sm_pv(f32x4* sc, float* m, float* lsum, f32x4* acco,
                                      const short* Vc, short* Pw, int q0, bool diag,
                                      int kb, int l15, int lg) {
  if (diag) {
#pragma unroll
    for (int nt = 0; nt < 4; ++nt) {
      const int k = kb + nt * 16 + l15;
#pragma unroll
      for (int r = 0; r < 4; ++r)
        if (k > q0 + lg * 4 + r) sc[nt][r] = -1e30f;
    }
  }
  float pm[4];
#pragma unroll
  for (int r = 0; r < 4; ++r)
    pm[r] = fmaxf(fmaxf(sc[0][r], sc[1][r]), fmaxf(sc[2][r], sc[3][r]));
#pragma unroll
  for (int r = 0; r < 4; ++r) {
    pm[r] = fmaxf(pm[r], __shfl_xor(pm[r], 1));
    pm[r] = fmaxf(pm[r], __shfl_xor(pm[r], 2));
    pm[r] = fmaxf(pm[r], __shfl_xor(pm[r], 4));
    pm[r] = fmaxf(pm[r], __shfl_xor(pm[r], 8));
  }
  // defer-max (T13): only rescale when the max moved by > 8
  float need = -1e30f;
#pragma unroll
  for (int r = 0; r < 4; ++r) need = fmaxf(need, pm[r] - m[r]);
  if (__any(need > 8.f)) {
#pragma unroll
    for (int r = 0; r < 4; ++r) {
      const float nm = fmaxf(m[r], pm[r]);
      const float alpha = __expf(m[r] - nm);
      m[r] = nm;
      lsum[r] *= alpha;
#pragma unroll
      for (int dt = 0; dt < 8; ++dt) acco[dt][r] *= alpha;
    }
  }
  float psum[4] = {0.f, 0.f, 0.f, 0.f};
#pragma unroll
  for (int nt = 0; nt < 4; ++nt)
#pragma unroll
    for (int r = 0; r < 4; ++r) {
      const float p = __expf(sc[nt][r] - m[r]);
      psum[r] += p;
      Pw[(lg * 4 + r) * 72 + nt * 16 + l15] = f2b(p);
    }
#pragma unroll
  for (int r = 0; r < 4; ++r) lsum[r] += psum[r];
#pragma unroll
  for (int kk = 0; kk < 2; ++kk) {
    bf16x8 ap = *(const bf16x8*)(Pw + l15 * 72 + kk * 32 + lg * 8);
#pragma unroll
    for (int dt = 0; dt < 8; ++dt) {
      const int vrow = dt * 16 + l15;
      bf16x8 bv = *(const bf16x8*)(Vc + vrow * 64 +
                                   (((kk * 64 + lg * 16) ^ ((vrow & 7) << 4)) >> 1));
      acco[dt] = mfma16(ap, bv, acco[dt]);
    }
  }
}

__device__ __forceinline__ void attn_writeout(f32x4* acco, float* lsum,
                                              short* __restrict__ AO, int b, int qh,
                                              int q0, int l15, int lg) {
  float ls[4];
#pragma unroll
  for (int r = 0; r < 4; ++r) {
    float t = lsum[r];
    t += __shfl_xor(t, 1);
    t += __shfl_xor(t, 2);
    t += __shfl_xor(t, 4);
    t += __shfl_xor(t, 8);
    ls[r] = 1.0f / t;
  }
  short* ob = AO + (size_t)(b * S_LEN + q0) * (NQH * DK) + qh * DK;
#pragma unroll
  for (int dt = 0; dt < 8; ++dt)
#pragma unroll
    for (int r = 0; r < 4; ++r)
      ob[(size_t)(lg * 4 + r) * (NQH * DK) + dt * 16 + l15] = f2b(acco[dt][r] * ls[r]);
}

// 1-D grid 512 blocks XCD-swizzled: x = q-tile pair (0..15), bh = b*16+qh (0..31).
// Block handles q-tiles qtA = x and qtB = 31-x -> 33 tile-computations each.
__global__ __launch_bounds__(256, 2) void attn_kernel(const short* __restrict__ Qr,
                                                      const short* __restrict__ Kr,
                                                      const short* __restrict__ Vt,
                                                      short* __restrict__ AO) {
  const int flat = blockIdx.x;
  const int nw = (flat & 7) * 64 + (flat >> 3);  // 512 = 8*64: 4 bh (1 KV group) per XCD
  const int qtA = nw & 15;
  const int bh = nw >> 4;
  const int qtB = 31 - qtA;
  const int b = bh >> 4, qh = bh & 15;
  const int kvh = qh >> 2;
  const short* Qb = Qr + (size_t)bh * S_LEN * DK;
  const short* Kb = Kr + (size_t)(b * NKVH + kvh) * S_LEN * DK;
  const short* Vb = Vt + (size_t)(b * NKVH + kvh) * DK * S_LEN;
  const int tid = threadIdx.x, lane = tid & 63, w = tid >> 6;
  const int l15 = lane & 15, lg = lane >> 4;

  __shared__ __align__(16) short KV[4][64 * 128];
  __shared__ __align__(16) short P[4][16][72];
  short* Pw = &P[w][0][0];

  const int q0A = qtA * 64 + w * 16, q0B = qtB * 64 + w * 16;
  bf16x8 aqA[4], aqB[4];
#pragma unroll
  for (int kk = 0; kk < 4; ++kk) {
    aqA[kk] = *(const bf16x8*)(Qb + (size_t)(q0A + l15) * DK + kk * 32 + lg * 8);
    aqB[kk] = *(const bf16x8*)(Qb + (size_t)(q0B + l15) * DK + kk * 32 + lg * 8);
  }

  f32x4 accoA[8] = {}, accoB[8] = {};
  float mA[4], lsA[4], mB[4], lsB[4];
#pragma unroll
  for (int r = 0; r < 4; ++r) { mA[r] = mB[r] = -1e30f; lsA[r] = lsB[r] = 0.f; }

  short* Kcur = KV[0]; short* Vcur = KV[1];
  short* Knxt = KV[2]; short* Vnxt = KV[3];

  stage_kv(Kb, Vb, 0, Kcur, Vcur, w, lane);
  asm volatile("s_waitcnt vmcnt(0)" ::: "memory");
  __syncthreads();

  for (int kt = 0; kt <= qtB; ++kt) {
    const int kb = kt * 64;
    if (kt < qtB) stage_kv(Kb, Vb, kb + 64, Knxt, Vnxt, w, lane);

    if (kt <= qtA) {
      f32x4 scB[4] = {}, scA[4] = {};
#pragma unroll
      for (int kk = 0; kk < 4; ++kk)
#pragma unroll
        for (int nt = 0; nt < 4; ++nt) {
          const int krow = nt * 16 + l15;
          bf16x8 bk = *(const bf16x8*)(Kcur + krow * 128 +
                                       (((kk * 64 + lg * 16) ^ ((krow & 7) << 4)) >> 1));
          scB[nt] = mfma16(aqB[kk], bk, scB[nt]);
          scA[nt] = mfma16(aqA[kk], bk, scA[nt]);
        }
      sm_pv(scB, mB, lsB, accoB, Vcur, Pw, q0B, false, kb, l15, lg);
      sm_pv(scA, mA, lsA, accoA, Vcur, Pw, q0A, kt == qtA, kb, l15, lg);
    } else {
      f32x4 scB[4] = {};
#pragma unroll
      for (int kk = 0; kk < 4; ++kk)
#pragma unroll
        for (int nt = 0; nt < 4; ++nt) {
          const int krow = nt * 16 + l15;
          bf16x8 bk = *(const bf16x8*)(Kcur + krow * 128 +
                                       (((kk * 64 + lg * 16) ^ ((krow & 7) << 4)) >> 1));
          scB[nt] = mfma16(aqB[kk], bk, scB[nt]);
        }
      sm_pv(scB, mB, lsB, accoB, Vcur, Pw, q0B, kt == qtB, kb, l15, lg);
    }

    asm volatile("s_waitcnt vmcnt(0)" ::: "memory");
    __syncthreads();
    short* t;
    t = Kcur; Kcur = Knxt; Knxt = t;
    t = Vcur; Vcur = Vnxt; Vnxt = t;
  }

  attn_writeout(accoB, lsB, AO, b, qh, q0B, l15, lg);
  attn_writeout(accoA, lsA, AO, b, qh, q0A, l15, lg);
}

// ---------------------------------------------------------------- launch
extern "C" void kernel_launch(void* const* d_in, const int* in_sizes, int n_in,
                              void* d_out, int out_size, void* d_ws, size_t ws_size,
                              hipStream_t stream) {
  const float* x = (const float*)d_in[0];
  // d_in[1] = mask (causal tril) — implemented analytically
  const float* Wq = (const float*)d_in[2];
  const float* Wk = (const float*)d_in[3];
  const float* Wv = (const float*)d_in[4];
  const float* Wfc = (const float*)d_in[5];
  const float* qg = (const float*)d_in[6];
  const float* kg = (const float*)d_in[7];

  short* ws = (short*)d_ws;
  short* xb = ws;                                   // 4096*2048 (also reused as AO)
  short* WqkvT = xb + (size_t)4096 * 2048;          // 3072*2048 = [WqT;WkT;WvT]
  short* WqT = WqkvT;
  short* WkT = WqT + (size_t)2048 * 2048;
  short* WvT = WkT + (size_t)512 * 2048;
  short* WfcT = WvT + (size_t)512 * 2048;           // 2048*2048
  short* Qr = WfcT + (size_t)2048 * 2048;           // 32*2048*128
  short* Kr = Qr + (size_t)32 * 2048 * 128;         // 8*2048*128
  short* Vt = Kr + (size_t)8 * 2048 * 128;          // 8*128*2048
  float* ropeT = (float*)(Vt + (size_t)8 * 128 * 2048);  // 2048*128 f32
  short* AO = xb;                                   // alias: x dead after QKV GEMM

  f32_to_bf16<<<(4096 * 2048 / 4 + 255) / 256, 256, 0, stream>>>(x, xb, 4096 * 2048 / 4);
  rope_table<<<(2048 * 64 + 255) / 256, 256, 0, stream>>>(ropeT);

  dim3 tb(32, 8);
  transpose_f2b<<<dim3(2048 / 32, 2048 / 32), tb, 0, stream>>>(Wq, WqT, 2048, 2048);
  transpose_f2b<<<dim3(512 / 32, 2048 / 32), tb, 0, stream>>>(Wk, WkT, 2048, 512);
  transpose_f2b<<<dim3(512 / 32, 2048 / 32), tb, 0, stream>>>(Wv, WvT, 2048, 512);
  transpose_f2b<<<dim3(2048 / 32, 2048 / 32), tb, 0, stream>>>(Wfc, WfcT, 2048, 2048);

  gemm_qkv<<<768, 256, 0, stream>>>(xb, WqkvT, Qr, Kr, Vt, qg, kg, ropeT);

  attn_kernel<<<512, 256, 0, stream>>>(Qr, Kr, Vt, AO);

  gemm_out<<<512, 256, 0, stream>>>(AO, WfcT, (float*)d_out);
}